// Round 12
// baseline (702.422 us; speedup 1.0000x reference)
//
#include <hip/hip_runtime.h>
#include <hip/hip_bf16.h>

#define DEVINL __device__ __forceinline__

typedef float f32x4 __attribute__((ext_vector_type(4)));
typedef unsigned short u16x8 __attribute__((ext_vector_type(8)));
typedef __bf16 bf16x8 __attribute__((ext_vector_type(8)));

static constexpr int NN = 40000;     // nodes
static constexpr int NE = 640000;    // edges (divisible by 256)
static constexpr int H  = 128;
static constexpr int NSCAN = 40;     // ceil(NN/1024)

// ---- ws layout (bytes) ----
static constexpr long O_HACC = 0;                       // f32 [NN][128]
static constexpr long O_H16  = 20480000;                // bf16 [NN][128]
static constexpr long O_DEG  = 30720000;                // f32 [NN] (deg_inv)
static constexpr long O_WP   = 30880000;                // prepped weights 22*32KB (fills gap exactly)
static constexpr long O_HDP  = 31600896;                // bf16 [NN][128] sigma-permuted
static constexpr long O_HSP  = 41840896;                // bf16 [NN][128] sigma-permuted
static constexpr long O_CNT  = 52080896;                // u32 [NN]
static constexpr long O_LOC  = 52240896;                // u32 [NN]
static constexpr long O_ROWP = 52400896;                // u32 [NN+1] (+pad)
static constexpr long O_CURS = 52560912;                // u32 [NN]
static constexpr long O_BSUM = 52720912;                // u32 [64]
static constexpr long O_PERM = 52721168;                // u32 [NE]
static constexpr long O_SRCS = 55281168;                // i32 [NE]
static constexpr long O_DSTS = 57841168;                // i32 [NE]
static constexpr long O_EA16 = 224241168;               // bf16 [NE][128] sorted
static constexpr long NEED_T2 = O_EA16 + (long)NE * H * 2;  // 388.1 MB

// prepped-weight blocks (16384 ushorts each):
// m0 e2n_W1(A)  m1 e2n_W2(K)  m2..10 {W1a,W1b,W1c}(A) per layer
// m11..13 W2(K)  m14..16 nW(A)  m17 outW1(A)
// m18 W1a_l1(K) m19 W1b_l1(K) m20 W1a_l2(K) m21 W1b_l2(K)
__host__ __device__ inline const unsigned short* wpm(const unsigned short* wp, int m) {
  return wp + m * 16384;
}

DEVINL unsigned short f2bf(float f) {
  unsigned int u = __float_as_uint(f);
  u += 0x7fffu + ((u >> 16) & 1u);     // round-to-nearest-even
  return (unsigned short)(u >> 16);
}
DEVINL float bf2f(unsigned short u) {
  return __uint_as_float(((unsigned int)u) << 16);
}

DEVINL f32x4 mfma16(u16x8 a, u16x8 b, f32x4 c) {
  return __builtin_amdgcn_mfma_f32_16x16x32_bf16(
      __builtin_bit_cast(bf16x8, a), __builtin_bit_cast(bf16x8, b), c, 0, 0, 0);
}

// ---------------- weight prep ----------------
// mode A: Wp[((ks*8+nb)*64+l)*8+j] = W[32ks + 8*(l>>4) + j][16nb + (l&15)]
// mode K: Wp[...]                  = W[4ks + (l>>4) + 16j][16nb + (l&15)]
struct PrepPtrs { const float* p[22]; };

__global__ void prep_all(PrepPtrs pp, unsigned short* __restrict__ wp) {
  constexpr int MODE[22] = {0,1, 0,0,0, 0,0,0, 0,0,0, 1,1,1, 0,0,0, 0, 1,1,1,1};
  int m = blockIdx.y;
  int idx = blockIdx.x * 256 + threadIdx.x;
  if (idx >= 16384) return;
  int j  = idx & 7, l = (idx >> 3) & 63, nb = (idx >> 9) & 7, ks = idx >> 12;
  int hi = l >> 4, lo = l & 15;
  int k = MODE[m] ? (4*ks + hi + 16*j) : (32*ks + 8*hi + j);
  int n = nb*16 + lo;
  wp[m * 16384 + idx] = f2bf(pp.p[m][k*128 + n]);
}

// ---------------- counting sort by dst ----------------
__global__ void hist_k(const int* __restrict__ dst, unsigned* __restrict__ cnt) {
  int e = blockIdx.x * 256 + threadIdx.x;
  atomicAdd(&cnt[dst[e]], 1u);
}

__global__ void scan1_k(const unsigned* __restrict__ cnt, unsigned* __restrict__ loc,
                        unsigned* __restrict__ bsum) {
  __shared__ unsigned sh[256];
  int t = threadIdx.x;
  int base = blockIdx.x * 1024 + t * 4;
  unsigned v[4]; unsigned s = 0;
  #pragma unroll
  for (int j = 0; j < 4; ++j) {
    v[j] = (base + j < NN) ? cnt[base + j] : 0u;
    s += v[j];
  }
  sh[t] = s; __syncthreads();
  #pragma unroll
  for (int off = 1; off < 256; off <<= 1) {
    unsigned y = (t >= off) ? sh[t - off] : 0u;
    __syncthreads();
    sh[t] += y;
    __syncthreads();
  }
  unsigned run = sh[t] - s;   // exclusive base for this thread
  #pragma unroll
  for (int j = 0; j < 4; ++j) {
    if (base + j < NN) loc[base + j] = run;
    run += v[j];
  }
  if (t == 255) bsum[blockIdx.x] = sh[255];
}

__global__ void scan2_k(unsigned* __restrict__ bsum) {
  int t = threadIdx.x;   // 64 threads, one wave
  unsigned orig = (t < NSCAN) ? bsum[t] : 0u;
  unsigned v = orig;
  #pragma unroll
  for (int off = 1; off < 64; off <<= 1) {
    unsigned y = __shfl_up(v, off);
    if (t >= off) v += y;
  }
  if (t < NSCAN) bsum[t] = v - orig;   // exclusive
}

__global__ void scan3_k(const unsigned* __restrict__ loc, const unsigned* __restrict__ bsum,
                        const unsigned* __restrict__ cnt, unsigned* __restrict__ rowPtr,
                        unsigned* __restrict__ cursor, float* __restrict__ deg_inv) {
  int i = blockIdx.x * 256 + threadIdx.x;
  if (i < NN) {
    unsigned r = loc[i] + bsum[i >> 10];
    rowPtr[i] = r;
    cursor[i] = r;
    deg_inv[i] = 1.0f / fmaxf((float)cnt[i], 1.0f);
  }
  if (i == NN) rowPtr[NN] = (unsigned)NE;
}

__global__ void scat_k(const int* __restrict__ src, const int* __restrict__ dst,
                       unsigned* __restrict__ cursor, unsigned* __restrict__ perm,
                       int* __restrict__ srcS, int* __restrict__ dstS) {
  int e = blockIdx.x * 256 + threadIdx.x;
  int d = dst[e];
  unsigned pos = atomicAdd(&cursor[d], 1u);
  perm[pos] = (unsigned)e;
  srcS[pos] = src[e];
  dstS[pos] = d;
}

// ---------------- xform0: Hdp = h0@W1a, Hsp = h0@W1b from f32 agg (sigma out) ----------------
__global__ __launch_bounds__(256) void node_xform(
    const float* __restrict__ hsrc,
    const unsigned short* __restrict__ wpa, const unsigned short* __restrict__ wpb,
    unsigned short* __restrict__ Hdp, unsigned short* __restrict__ Hsp) {
  const int tid = threadIdx.x;
  const int wave = tid >> 6, lane = tid & 63;
  const int hi = lane >> 4, lo = lane & 15;
  const int n0w = blockIdx.x * 256 + wave * 64;

  // A-frags (shared by both outputs): load f32, convert
  u16x8 a[4][4];   // [s][mf]
  #pragma unroll
  for (int s = 0; s < 4; ++s)
    #pragma unroll
    for (int mf = 0; mf < 4; ++mf) {
      int n = n0w + 16 * mf + lo; if (n >= NN) n = NN - 1;
      f32x4 f0 = *(const f32x4*)(hsrc + (long)n * 128 + s * 32 + hi * 8);
      f32x4 f1 = *(const f32x4*)(hsrc + (long)n * 128 + s * 32 + hi * 8 + 4);
      u16x8 t;
      #pragma unroll
      for (int j = 0; j < 4; ++j) { t[j] = f2bf(f0[j]); t[4+j] = f2bf(f1[j]); }
      a[s][mf] = t;
    }

  #pragma unroll
  for (int out = 0; out < 2; ++out) {
    const unsigned short* wp = out ? wpb : wpa;
    unsigned short* dp = out ? Hsp : Hdp;
    f32x4 acc[4][8];
    #pragma unroll
    for (int mf = 0; mf < 4; ++mf)
      #pragma unroll
      for (int nb = 0; nb < 8; ++nb) acc[mf][nb] = (f32x4)(0.0f);
    #pragma unroll
    for (int s = 0; s < 4; ++s)
      #pragma unroll
      for (int nb = 0; nb < 8; ++nb) {
        u16x8 b = *(const u16x8*)(wp + ((s * 8 + nb) * 64 + lane) * 8);
        #pragma unroll
        for (int mf = 0; mf < 4; ++mf) acc[mf][nb] = mfma16(a[s][mf], b, acc[mf][nb]);
      }
    #pragma unroll
    for (int mf = 0; mf < 4; ++mf)
      #pragma unroll
      for (int r = 0; r < 4; ++r) {
        int n = n0w + 16 * mf + 4 * hi + r;
        if (n < NN) {
          u16x8 pack;
          #pragma unroll
          for (int nb = 0; nb < 8; ++nb) pack[nb] = f2bf(acc[mf][nb][r]);
          *(u16x8*)(dp + (long)n * 128 + 8 * lo) = pack;   // sigma: col 16nb+lo -> 8lo+nb
        }
      }
  }
}

// ---------------- node_fused: h=relu(agg@Wn+bn) -> h16 [+ Hdp/Hsp for next layer] ----------
// Wn (A-mode), W1a'/W1b' (KAPPA-prepped) read from global (L2-resident, small grid).
// XF path: h -> sigma stripe -> kappa A-frags -> GEMM -> sigma Hdp/Hsp (k12-proven pattern).
template<bool XF>
__global__ __launch_bounds__(256) void node_fused(
    const float* __restrict__ agg, const unsigned short* __restrict__ wn,
    const float* __restrict__ bias,
    const unsigned short* __restrict__ w1aK, const unsigned short* __restrict__ w1bK,
    unsigned short* __restrict__ h16out,
    unsigned short* __restrict__ Hdp, unsigned short* __restrict__ Hsp) {
  __shared__ char smem[16384];   // 4 wave-private stripes
  const int tid = threadIdx.x;
  const int wave = tid >> 6, lane = tid & 63;
  const int hi = lane >> 4, lo = lane & 15;
  const int n0w = blockIdx.x * 256 + wave * 64;
  char* sstripe = smem + wave * 4096;

  float bv[8];
  #pragma unroll
  for (int nb = 0; nb < 8; ++nb) bv[nb] = bias[nb * 16 + lo];

  f32x4 acc[4][8];
  #pragma unroll
  for (int mf = 0; mf < 4; ++mf)
    #pragma unroll
    for (int nb = 0; nb < 8; ++nb) acc[mf][nb] = (f32x4)(0.0f);

  #pragma unroll
  for (int s = 0; s < 4; ++s) {
    u16x8 a[4];
    #pragma unroll
    for (int mf = 0; mf < 4; ++mf) {
      int n = n0w + 16 * mf + lo; if (n >= NN) n = NN - 1;
      f32x4 f0 = *(const f32x4*)(agg + (long)n * 128 + s * 32 + hi * 8);
      f32x4 f1 = *(const f32x4*)(agg + (long)n * 128 + s * 32 + hi * 8 + 4);
      u16x8 t;
      #pragma unroll
      for (int j = 0; j < 4; ++j) { t[j] = f2bf(f0[j]); t[4+j] = f2bf(f1[j]); }
      a[mf] = t;
    }
    #pragma unroll
    for (int nb = 0; nb < 8; ++nb) {
      u16x8 b = *(const u16x8*)(wn + ((s * 8 + nb) * 64 + lane) * 8);
      #pragma unroll
      for (int mf = 0; mf < 4; ++mf) acc[mf][nb] = mfma16(a[mf], b, acc[mf][nb]);
    }
  }

  #pragma unroll
  for (int mf = 0; mf < 4; ++mf) {
    // epilogue: h = relu(acc + b) -> bf16 packs
    u16x8 hp[4];
    #pragma unroll
    for (int r = 0; r < 4; ++r)
      #pragma unroll
      for (int nb = 0; nb < 8; ++nb)
        hp[r][nb] = f2bf(fmaxf(acc[mf][nb][r] + bv[nb], 0.0f));

    // h16 direct stores (D-layout scalar, node_pass-proven)
    #pragma unroll
    for (int nb = 0; nb < 8; ++nb)
      #pragma unroll
      for (int r = 0; r < 4; ++r) {
        int n = n0w + 16 * mf + 4 * hi + r;
        if (n < NN) h16out[(long)n * 128 + nb * 16 + lo] = hp[r][nb];
      }

    if (XF) {
      // sigma stripe write
      #pragma unroll
      for (int r = 0; r < 4; ++r) {
        int er = 4 * hi + r;
        *(u16x8*)(sstripe + er * 256 + ((lo * 16) ^ ((er & 7) << 4))) = hp[r];
      }
      // two GEMMs off the same stripe A-frags (kappa B)
      #pragma unroll
      for (int out = 0; out < 2; ++out) {
        const unsigned short* wb = out ? w1bK : w1aK;
        unsigned short* dp = out ? Hsp : Hdp;
        f32x4 a2[8];
        #pragma unroll
        for (int nb = 0; nb < 8; ++nb) a2[nb] = (f32x4)(0.0f);
        #pragma unroll
        for (int s2 = 0; s2 < 4; ++s2) {
          u16x8 a = *(const u16x8*)(sstripe + lo * 256 +
                                    (((4 * s2 + hi) * 16) ^ ((lo & 7) << 4)));
          #pragma unroll
          for (int nb = 0; nb < 8; ++nb) {
            u16x8 b = *(const u16x8*)(wb + ((s2 * 8 + nb) * 64 + lane) * 8);
            a2[nb] = mfma16(a, b, a2[nb]);
          }
        }
        #pragma unroll
        for (int r = 0; r < 4; ++r) {
          int n = n0w + 16 * mf + 4 * hi + r;
          if (n < NN) {
            u16x8 pack;
            #pragma unroll
            for (int nb = 0; nb < 8; ++nb) pack[nb] = f2bf(a2[nb][r]);
            *(u16x8*)(dp + (long)n * 128 + 8 * lo) = pack;
          }
        }
      }
    }
  }
}

// ---------------- K12 (fused GEMM1+GEMM2+segment-sum, two-phase) ----------------
// Phase A (main loop): asm load pipeline, GEMM1 -> stripe -> GEMM2, m packed to regs.
// Phase B (after last wait): stripe per mf -> segmented sum -> boundary atomics.
// Atomics no longer precede any vmcnt gate -> static credits, no retire stalls.
// LDS (dynamic 81920): [0,32K) W1; [32K,64K) W2; [64K,80K) 4 wave-stripes.
template<int EAM, bool EAST, bool GATH>
__global__ __launch_bounds__(256, 2) void k12_pass(
    const float* __restrict__ ea32, unsigned short* __restrict__ ea16,
    const unsigned* __restrict__ perm,
    const unsigned short* __restrict__ w1p, const unsigned short* __restrict__ w2p,
    const float* __restrict__ b1, const float* __restrict__ b2,
    const unsigned short* __restrict__ Hdp, const unsigned short* __restrict__ Hsp,
    const int* __restrict__ srcS, const int* __restrict__ dstS,
    const float* __restrict__ deg_inv, float* __restrict__ hacc) {
  extern __shared__ char smem[];
  const int tid = threadIdx.x;
  const int wave = tid >> 6, lane = tid & 63;
  const int hi = lane >> 4, lo = lane & 15;

  // bijective XCD swizzle: contiguous dst-chunk per XCD
  const int nwg = gridDim.x;
  const int xcd = blockIdx.x & 7, bbase = blockIdx.x >> 3;
  const int qc = nwg >> 3, rc = nwg & 7;
  const int bid = (xcd < rc ? xcd * (qc + 1) : rc * (qc + 1) + (xcd - rc) * qc) + bbase;
  const long e0w = (long)bid * 256 + wave * 64;
  char* sstripe = smem + 65536 + wave * 4096;

  constexpr int LB = (EAM == 0 ? 8 : 4) + (GATH ? 8 : 0);   // asm loads / batch
  constexpr int SB = (EAM == 0 && EAST) ? 4 : 0;            // static stores / iter

  unsigned pId[4];
  int dId[4], sId[4];
  float dsc[4];
  #pragma unroll
  for (int mf = 0; mf < 4; ++mf) {
    if (EAM == 0) pId[mf] = perm[e0w + 16 * mf + lo];
    dId[mf] = dstS[e0w + 16 * mf + lo];
    if (GATH) {
      sId[mf] = srcS[e0w + 16 * mf + lo];
      dsc[mf] = deg_inv[dId[mf]];
    }
  }

  float b1v[8], b2v[8];
  #pragma unroll
  for (int nb = 0; nb < 8; ++nb) { b1v[nb] = b1[nb * 16 + lo]; b2v[nb] = b2[nb * 16 + lo]; }

  // double-buffered operand sets (asm outputs — tied at the waits, can't be sunk)
  u16x8 eaA[4], eaB[4], gdA[4], gsA[4], gdB[4], gsB[4];
  f32x4 efA[8], efB[8];
  u16x8 mp0[4], mp1[4], mp2[4], mp3[4];   // m-tiles (bf16 packed), static names

  auto issue = [&](int mf, u16x8 (&ea)[4], f32x4 (&ef)[8],
                   u16x8 (&gd)[4], u16x8 (&gs)[4]) {
    if (EAM == 1) {
      #pragma unroll
      for (int s = 0; s < 4; ++s) {
        const unsigned short* p = ea16 + (e0w + 16 * mf + lo) * 128 + s * 32 + hi * 8;
        asm volatile("global_load_dwordx4 %0, %1, off" : "=&v"(ea[s]) : "v"(p) : "memory");
      }
    } else {
      #pragma unroll
      for (int s = 0; s < 4; ++s) {
        const float* p = ea32 + (long)pId[mf] * 128 + s * 32 + hi * 8;
        asm volatile("global_load_dwordx4 %0, %1, off" : "=&v"(ef[2*s])   : "v"(p)     : "memory");
        asm volatile("global_load_dwordx4 %0, %1, off" : "=&v"(ef[2*s+1]) : "v"(p + 4) : "memory");
      }
    }
    if (GATH) {
      #pragma unroll
      for (int r = 0; r < 4; ++r) {
        int rd = __shfl(dId[mf], 4 * hi + r);
        int rs = __shfl(sId[mf], 4 * hi + r);
        const unsigned short* pd = Hdp + (long)rd * 128 + 8 * lo;
        const unsigned short* ps = Hsp + (long)rs * 128 + 8 * lo;
        asm volatile("global_load_dwordx4 %0, %1, off" : "=&v"(gd[r]) : "v"(pd) : "memory");
        asm volatile("global_load_dwordx4 %0, %1, off" : "=&v"(gs[r]) : "v"(ps) : "memory");
      }
    }
  };

  issue(0, eaA, efA, gdA, gsA);   // batch0 lands under weight staging + barrier

  { // stage W1 + W2 into LDS (once)
    const u16x8* g1 = (const u16x8*)w1p;
    u16x8* l1 = (u16x8*)smem;
    #pragma unroll
    for (int i = 0; i < 8; ++i) l1[i * 256 + tid] = g1[i * 256 + tid];
    const u16x8* g2 = (const u16x8*)w2p;
    u16x8* l2 = (u16x8*)(smem + 32768);
    #pragma unroll
    for (int i = 0; i < 8; ++i) l2[i * 256 + tid] = g2[i * 256 + tid];
  }
  __syncthreads();

  // ---------------- Phase A ----------------
  #pragma unroll
  for (int mf = 0; mf < 4; ++mf) {
    u16x8 (&ea)[4] = (mf & 1) ? eaB : eaA;
    f32x4 (&ef)[8] = (mf & 1) ? efB : efA;
    u16x8 (&gd)[4] = (mf & 1) ? gdB : gdA;
    u16x8 (&gs)[4] = (mf & 1) ? gsB : gsA;
    if (mf < 3)
      issue(mf + 1, (mf & 1) ? eaA : eaB, (mf & 1) ? efA : efB,
            (mf & 1) ? gdA : gdB, (mf & 1) ? gsA : gsB);

    // gate on batch(mf): newer = loads(mf+1) + EAST-stores(mf-1) — all static now
    if (EAM == 1) {
      if (GATH) {
        asm volatile("s_waitcnt vmcnt(%12)"
          : "+v"(ea[0]), "+v"(ea[1]), "+v"(ea[2]), "+v"(ea[3]),
            "+v"(gd[0]), "+v"(gd[1]), "+v"(gd[2]), "+v"(gd[3]),
            "+v"(gs[0]), "+v"(gs[1]), "+v"(gs[2]), "+v"(gs[3])
          : "n"((mf < 3 ? LB : 0) + (mf > 0 ? SB : 0)));
      } else {
        asm volatile("s_waitcnt vmcnt(%4)"
          : "+v"(ea[0]), "+v"(ea[1]), "+v"(ea[2]), "+v"(ea[3])
          : "n"((mf < 3 ? LB : 0) + (mf > 0 ? SB : 0)));
      }
    } else if (GATH) {
      asm volatile("s_waitcnt vmcnt(%16)"
        : "+v"(ef[0]), "+v"(ef[1]), "+v"(ef[2]), "+v"(ef[3]),
          "+v"(ef[4]), "+v"(ef[5]), "+v"(ef[6]), "+v"(ef[7]),
          "+v"(gd[0]), "+v"(gd[1]), "+v"(gd[2]), "+v"(gd[3]),
          "+v"(gs[0]), "+v"(gs[1]), "+v"(gs[2]), "+v"(gs[3])
        : "n"((mf < 3 ? LB : 0) + (mf > 0 ? SB : 0)));
    } else {
      asm volatile("s_waitcnt vmcnt(%8)"
        : "+v"(ef[0]), "+v"(ef[1]), "+v"(ef[2]), "+v"(ef[3]),
          "+v"(ef[4]), "+v"(ef[5]), "+v"(ef[6]), "+v"(ef[7])
        : "n"((mf < 3 ? LB : 0) + (mf > 0 ? SB : 0)));
    }

    if (EAM == 0) {   // convert f32 -> bf16 (and optionally store sorted ea16)
      #pragma unroll
      for (int s = 0; s < 4; ++s) {
        u16x8 t;
        #pragma unroll
        for (int j = 0; j < 4; ++j) { t[j] = f2bf(ef[2*s][j]); t[4+j] = f2bf(ef[2*s+1][j]); }
        if (EAST)
          *(u16x8*)(ea16 + (e0w + 16 * mf + lo) * 128 + s * 32 + hi * 8) = t;
        ea[s] = t;
      }
    }

    // ---- GEMM1 (acc starts at 0; gathers added after) ----
    f32x4 acc[8];
    #pragma unroll
    for (int nb = 0; nb < 8; ++nb) acc[nb] = (f32x4)(0.0f);
    #pragma unroll
    for (int s = 0; s < 4; ++s)
      #pragma unroll
      for (int nb = 0; nb < 8; ++nb) {
        u16x8 b = *(const u16x8*)(smem + ((s * 8 + nb) << 10) + (lane << 4));
        acc[nb] = mfma16(ea[s], b, acc[nb]);
      }
    if (GATH) {
      #pragma unroll
      for (int nb = 0; nb < 8; ++nb)
        #pragma unroll
        for (int r = 0; r < 4; ++r)
          acc[nb][r] += bf2f(gd[r][nb]) + bf2f(gs[r][nb]);
    }

    // ---- epilogue1: bias+relu -> bf16 -> sigma stripe ----
    #pragma unroll
    for (int r = 0; r < 4; ++r) {
      int er = 4 * hi + r;
      u16x8 pack;
      #pragma unroll
      for (int nb = 0; nb < 8; ++nb)
        pack[nb] = f2bf(fmaxf(acc[nb][r] + b1v[nb], 0.0f));
      *(u16x8*)(sstripe + er * 256 + ((lo * 16) ^ ((er & 7) << 4))) = pack;
    }

    // ---- GEMM2 (wave-private stripe; acc reused) ----
    #pragma unroll
    for (int nb = 0; nb < 8; ++nb) acc[nb] = (f32x4)(0.0f);
    #pragma unroll
    for (int s2 = 0; s2 < 4; ++s2) {
      u16x8 a = *(const u16x8*)(sstripe + lo * 256 +
                                (((4 * s2 + hi) * 16) ^ ((lo & 7) << 4)));
      #pragma unroll
      for (int nb = 0; nb < 8; ++nb) {
        u16x8 b = *(const u16x8*)(smem + 32768 + ((s2 * 8 + nb) << 10) + (lane << 4));
        acc[nb] = mfma16(a, b, acc[nb]);
      }
    }

    // ---- epilogue2: +bias -> bf16 packs kept in registers ----
    u16x8 (&mp)[4] = (mf == 0) ? mp0 : (mf == 1) ? mp1 : (mf == 2) ? mp2 : mp3;
    #pragma unroll
    for (int r = 0; r < 4; ++r)
      #pragma unroll
      for (int nb = 0; nb < 8; ++nb)
        mp[r][nb] = f2bf(acc[nb][r] + b2v[nb]);
  }

  // ---------------- Phase B: segment-sum + atomics (no vmcnt gates follow) ----------------
  float runA = 0.0f, runB = 0.0f, scur = 1.0f;
  int dcur = -1;
  const int cA = 16 * ((2 * lane) & 7) + (lane >> 2);
  const int cB = 16 * ((2 * lane + 1) & 7) + (lane >> 2);

  #pragma unroll
  for (int mf = 0; mf < 4; ++mf) {
    u16x8 (&mp)[4] = (mf == 0) ? mp0 : (mf == 1) ? mp1 : (mf == 2) ? mp2 : mp3;
    #pragma unroll
    for (int r = 0; r < 4; ++r) {
      int er = 4 * hi + r;
      *(u16x8*)(sstripe + er * 256 + ((lo * 16) ^ ((er & 7) << 4))) = mp[r];
    }
    #pragma unroll
    for (int er = 0; er < 16; ++er) {
      int d = __shfl(dId[mf], er);
      float s = GATH ? __shfl(dsc[mf], er) : 1.0f;
      if (d != dcur) {
        if (dcur >= 0) {
          unsafeAtomicAdd(&hacc[(long)dcur * 128 + cA], runA * scur);
          unsafeAtomicAdd(&hacc[(long)dcur * 128 + cB], runB * scur);
        }
        runA = 0.0f; runB = 0.0f; dcur = d; scur = s;
      }
      unsigned pr = *(const unsigned*)(sstripe + er * 256 +
                                       ((lane * 4) ^ ((er & 7) << 4)));
      runA += bf2f((unsigned short)(pr & 0xffffu));
      runB += bf2f((unsigned short)(pr >> 16));
    }
  }
  if (dcur >= 0) {
    unsafeAtomicAdd(&hacc[(long)dcur * 128 + cA], runA * scur);
    unsafeAtomicAdd(&hacc[(long)dcur * 128 + cB], runB * scur);
  }
}

// ---------------- output head ----------------
__global__ __launch_bounds__(256) void out_pass(
    const unsigned short* __restrict__ h16, const unsigned short* __restrict__ wp,
    const float* __restrict__ ob1, const float* __restrict__ oW2,
    const float* __restrict__ ob2, float* __restrict__ out) {
  __shared__ char smem[49152];
  const int tid = threadIdx.x;
  const int wave = tid >> 6, lane = tid & 63;
  const int hi = lane >> 4, lo = lane & 15;
  const int n0 = blockIdx.x * 64;
  const int r = tid >> 2, q = tid & 3;

  #pragma unroll
  for (int s = 0; s < 4; ++s) {
    u16x8 t = *(const u16x8*)(h16 + (long)(n0 + r) * 128 + s * 32 + q * 8);
    *(u16x8*)(smem + s * 4096 + (((r >> 4) * 64 + q * 16 + (r & 15)) << 4)) = t;
  }
  {
    const u16x8* g = (const u16x8*)wp;
    u16x8* l = (u16x8*)(smem + 16384);
    #pragma unroll
    for (int i = 0; i < 8; ++i) l[i * 256 + tid] = g[i * 256 + tid];
  }
  __syncthreads();

  f32x4 acc[8];
  #pragma unroll
  for (int nb = 0; nb < 8; ++nb) acc[nb] = (f32x4)(0.0f);
  #pragma unroll
  for (int s = 0; s < 4; ++s) {
    u16x8 a = *(const u16x8*)(smem + s * 4096 + wave * 1024 + (lane << 4));
    #pragma unroll
    for (int nb = 0; nb < 8; ++nb) {
      u16x8 b = *(const u16x8*)(smem + 16384 + ((s * 8 + nb) << 10) + (lane << 4));
      acc[nb] = mfma16(a, b, acc[nb]);
    }
  }
  float b1v[8], w2v[8][3];
  #pragma unroll
  for (int nb = 0; nb < 8; ++nb) {
    b1v[nb] = ob1[nb * 16 + lo];
    #pragma unroll
    for (int o = 0; o < 3; ++o) w2v[nb][o] = oW2[(nb * 16 + lo) * 3 + o];
  }
  #pragma unroll
  for (int rr = 0; rr < 4; ++rr) {
    float p0 = 0.f, p1 = 0.f, p2 = 0.f;
    #pragma unroll
    for (int nb = 0; nb < 8; ++nb) {
      float t = fmaxf(acc[nb][rr] + b1v[nb], 0.0f);
      p0 += t * w2v[nb][0]; p1 += t * w2v[nb][1]; p2 += t * w2v[nb][2];
    }
    #pragma unroll
    for (int off = 1; off < 16; off <<= 1) {
      p0 += __shfl_xor(p0, off); p1 += __shfl_xor(p1, off); p2 += __shfl_xor(p2, off);
    }
    if (lo == 0) {
      int node = n0 + 16 * wave + 4 * hi + rr;
      out[(long)node * 3 + 0] = p0 + ob2[0];
      out[(long)node * 3 + 1] = p1 + ob2[1];
      out[(long)node * 3 + 2] = p2 + ob2[2];
    }
  }
}

// ---------------- host ----------------
extern "C" void kernel_launch(void* const* d_in, const int* in_sizes, int n_in,
                              void* d_out, int out_size, void* d_ws, size_t ws_size,
                              hipStream_t stream) {
  const int*   ei     = (const int*)d_in[1];
  const int*   srcIds = ei;
  const int*   dstIds = ei + NE;
  const float* ea     = (const float*)d_in[2];
  const float* e2nb1  = (const float*)d_in[4];
  const float* e2nb2  = (const float*)d_in[6];
  const float* eW1    = (const float*)d_in[7];
  const float* eb1    = (const float*)d_in[8];
  const float* eW2    = (const float*)d_in[9];
  const float* eb2    = (const float*)d_in[10];
  const float* nW     = (const float*)d_in[11];
  const float* nb_    = (const float*)d_in[12];
  const float* ob1    = (const float*)d_in[14];
  const float* oW2    = (const float*)d_in[15];
  const float* ob2    = (const float*)d_in[16];
  float* out = (float*)d_out;

  char* ws = (char*)d_ws;
  float* hacc = (float*)(ws + O_HACC);
  unsigned short* h16 = (unsigned short*)(ws + O_H16);
  float* deg_inv = (float*)(ws + O_DEG);
  unsigned short* wp = (unsigned short*)(ws + O_WP);
  unsigned short* Hdp = (unsigned short*)(ws + O_HDP);
  unsigned short* Hsp = (unsigned short*)(ws + O_HSP);
  unsigned* cnt    = (unsigned*)(ws + O_CNT);
  unsigned* loc    = (unsigned*)(ws + O_LOC);
  unsigned* rowPtr = (unsigned*)(ws + O_ROWP);
  unsigned* cursor = (unsigned*)(ws + O_CURS);
  unsigned* bsum   = (unsigned*)(ws + O_BSUM);
  unsigned* perm   = (unsigned*)(ws + O_PERM);
  int* srcS        = (int*)(ws + O_SRCS);
  int* dstS        = (int*)(ws + O_DSTS);
  unsigned short* ea16 = (unsigned short*)(ws + O_EA16);
  const bool tier2 = ws_size >= (size_t)NEED_T2;

  PrepPtrs pp;
  pp.p[0] = (const float*)d_in[3];
  pp.p[1] = (const float*)d_in[5];
  for (int l = 0; l < 3; ++l) {
    pp.p[2 + 3*l] = eW1 + l * 49152;             // W1a (A)
    pp.p[3 + 3*l] = eW1 + l * 49152 + 16384;     // W1b (A)
    pp.p[4 + 3*l] = eW1 + l * 49152 + 32768;     // W1c (A)
    pp.p[11 + l]  = eW2 + l * 16384;             // W2 (kappa)
    pp.p[14 + l]  = nW  + l * 16384;             // nW (A)
  }
  pp.p[17] = (const float*)d_in[13];
  pp.p[18] = eW1 + 1 * 49152;                    // W1a_l1 (kappa)
  pp.p[19] = eW1 + 1 * 49152 + 16384;            // W1b_l1 (kappa)
  pp.p[20] = eW1 + 2 * 49152;                    // W1a_l2 (kappa)
  pp.p[21] = eW1 + 2 * 49152 + 16384;            // W1b_l2 (kappa)

  prep_all<<<dim3(64, 22), 256, 0, stream>>>(pp, wp);

  // counting sort by dst + deg_inv
  hipMemsetAsync(cnt, 0, (size_t)NN * 4, stream);
  hist_k<<<NE / 256, 256, 0, stream>>>(dstIds, cnt);
  scan1_k<<<NSCAN, 256, 0, stream>>>(cnt, loc, bsum);
  scan2_k<<<1, 64, 0, stream>>>(bsum);
  scan3_k<<<(NN + 256) / 256, 256, 0, stream>>>(loc, bsum, cnt, rowPtr, cursor, deg_inv);
  scat_k<<<NE / 256, 256, 0, stream>>>(srcIds, dstIds, cursor, perm, srcS, dstS);

  // ---- e2n: fused edge-MLP + scatter-sum -> hacc = h0 (f32) ----
  hipMemsetAsync(hacc, 0, (size_t)NN * H * 4, stream);
  if (tier2)
    k12_pass<0, true, false><<<NE / 256, 256, 81920, stream>>>(
        ea, ea16, perm, wpm(wp, 0), wpm(wp, 1), e2nb1, e2nb2,
        nullptr, nullptr, srcS, dstS, deg_inv, hacc);
  else
    k12_pass<0, false, false><<<NE / 256, 256, 81920, stream>>>(
        ea, nullptr, perm, wpm(wp, 0), wpm(wp, 1), e2nb1, e2nb2,
        nullptr, nullptr, srcS, dstS, deg_inv, hacc);

  // xform0: Hdp/Hsp for layer 0 straight from f32 h0
  node_xform<<<(NN + 255) / 256, 256, 0, stream>>>(
      hacc, wpm(wp, 2), wpm(wp, 3), Hdp, Hsp);

  for (int l = 0; l < 3; ++l) {
    hipMemsetAsync(hacc, 0, (size_t)NN * H * 4, stream);
    if (tier2)
      k12_pass<1, false, true><<<NE / 256, 256, 81920, stream>>>(
          ea, ea16, perm, wpm(wp, 4 + 3*l), wpm(wp, 11 + l),
          eb1 + l * 128, eb2 + l * 128, Hdp, Hsp, srcS, dstS, deg_inv, hacc);
    else
      k12_pass<0, false, true><<<NE / 256, 256, 81920, stream>>>(
          ea, nullptr, perm, wpm(wp, 4 + 3*l), wpm(wp, 11 + l),
          eb1 + l * 128, eb2 + l * 128, Hdp, Hsp, srcS, dstS, deg_inv, hacc);
    if (l < 2)
      node_fused<true><<<(NN + 255) / 256, 256, 0, stream>>>(
          hacc, wpm(wp, 14 + l), nb_ + l * 128,
          wpm(wp, 18 + 2*l), wpm(wp, 19 + 2*l), h16, Hdp, Hsp);
    else
      node_fused<false><<<(NN + 255) / 256, 256, 0, stream>>>(
          hacc, wpm(wp, 14 + l), nb_ + l * 128,
          nullptr, nullptr, h16, nullptr, nullptr);
  }

  out_pass<<<NN / 64, 256, 0, stream>>>(h16, wpm(wp, 17), ob1, oW2, ob2, out);
}

// Round 13
// 636.934 us; speedup vs baseline: 1.1028x; 1.1028x over previous
//
#include <hip/hip_runtime.h>
#include <hip/hip_bf16.h>

#define DEVINL __device__ __forceinline__

typedef float f32x4 __attribute__((ext_vector_type(4)));
typedef unsigned short u16x8 __attribute__((ext_vector_type(8)));
typedef __bf16 bf16x8 __attribute__((ext_vector_type(8)));

static constexpr int NN = 40000;     // nodes
static constexpr int NE = 640000;    // edges (divisible by 256)
static constexpr int H  = 128;
static constexpr int NSCAN = 40;     // ceil(NN/1024)

// ---- ws layout (bytes) ----
static constexpr long O_HACC = 0;                       // f32 [NN][128]
static constexpr long O_H16  = 20480000;                // bf16 [NN][128]
static constexpr long O_DEG  = 30720000;                // f32 [NN] (deg_inv)
static constexpr long O_WP   = 30880000;                // prepped weights 18*32KB
static constexpr long O_HDP  = 31600896;                // bf16 [NN][128] sigma-permuted
static constexpr long O_HSP  = 41840896;                // bf16 [NN][128] sigma-permuted
static constexpr long O_CNT  = 52080896;                // u32 [NN]
static constexpr long O_LOC  = 52240896;                // u32 [NN]
static constexpr long O_ROWP = 52400896;                // u32 [NN+1] (+pad)
static constexpr long O_CURS = 52560912;                // u32 [NN]
static constexpr long O_BSUM = 52720912;                // u32 [64]
static constexpr long O_PERM = 52721168;                // u32 [NE]
static constexpr long O_SRCS = 55281168;                // i32 [NE]
static constexpr long O_DSTS = 57841168;                // i32 [NE]
static constexpr long O_EA16 = 224241168;               // bf16 [NE][128] sorted
static constexpr long NEED_T2 = O_EA16 + (long)NE * H * 2;  // 388.1 MB

// prepped-weight blocks (16384 ushorts each):
// m0 e2n_W1(A)  m1 e2n_W2(K)  m2..10 {W1a,W1b,W1c}(A) per layer
// m11..13 W2(K) per layer     m14..16 nW(A)  m17 outW1(A)
__host__ __device__ inline const unsigned short* wpm(const unsigned short* wp, int m) {
  return wp + m * 16384;
}

DEVINL unsigned short f2bf(float f) {
  unsigned int u = __float_as_uint(f);
  u += 0x7fffu + ((u >> 16) & 1u);     // round-to-nearest-even
  return (unsigned short)(u >> 16);
}
DEVINL float bf2f(unsigned short u) {
  return __uint_as_float(((unsigned int)u) << 16);
}

DEVINL f32x4 mfma16(u16x8 a, u16x8 b, f32x4 c) {
  return __builtin_amdgcn_mfma_f32_16x16x32_bf16(
      __builtin_bit_cast(bf16x8, a), __builtin_bit_cast(bf16x8, b), c, 0, 0, 0);
}

// ---------------- weight prep ----------------
// mode A: Wp[((ks*8+nb)*64+l)*8+j] = W[32ks + 8*(l>>4) + j][16nb + (l&15)]
// mode K: Wp[...]                  = W[4ks + (l>>4) + 16j][16nb + (l&15)]
struct PrepPtrs { const float* p[18]; };

__global__ void prep_all(PrepPtrs pp, unsigned short* __restrict__ wp) {
  constexpr int MODE[18] = {0,1, 0,0,0, 0,0,0, 0,0,0, 1,1,1, 0,0,0, 0};
  int m = blockIdx.y;
  int idx = blockIdx.x * 256 + threadIdx.x;
  if (idx >= 16384) return;
  int j  = idx & 7, l = (idx >> 3) & 63, nb = (idx >> 9) & 7, ks = idx >> 12;
  int hi = l >> 4, lo = l & 15;
  int k = MODE[m] ? (4*ks + hi + 16*j) : (32*ks + 8*hi + j);
  int n = nb*16 + lo;
  wp[m * 16384 + idx] = f2bf(pp.p[m][k*128 + n]);
}

// ---------------- counting sort by dst ----------------
__global__ void hist_k(const int* __restrict__ dst, unsigned* __restrict__ cnt) {
  int e = blockIdx.x * 256 + threadIdx.x;
  atomicAdd(&cnt[dst[e]], 1u);
}

__global__ void scan1_k(const unsigned* __restrict__ cnt, unsigned* __restrict__ loc,
                        unsigned* __restrict__ bsum) {
  __shared__ unsigned sh[256];
  int t = threadIdx.x;
  int base = blockIdx.x * 1024 + t * 4;
  unsigned v[4]; unsigned s = 0;
  #pragma unroll
  for (int j = 0; j < 4; ++j) {
    v[j] = (base + j < NN) ? cnt[base + j] : 0u;
    s += v[j];
  }
  sh[t] = s; __syncthreads();
  #pragma unroll
  for (int off = 1; off < 256; off <<= 1) {
    unsigned y = (t >= off) ? sh[t - off] : 0u;
    __syncthreads();
    sh[t] += y;
    __syncthreads();
  }
  unsigned run = sh[t] - s;   // exclusive base for this thread
  #pragma unroll
  for (int j = 0; j < 4; ++j) {
    if (base + j < NN) loc[base + j] = run;
    run += v[j];
  }
  if (t == 255) bsum[blockIdx.x] = sh[255];
}

__global__ void scan2_k(unsigned* __restrict__ bsum) {
  int t = threadIdx.x;   // 64 threads, one wave
  unsigned orig = (t < NSCAN) ? bsum[t] : 0u;
  unsigned v = orig;
  #pragma unroll
  for (int off = 1; off < 64; off <<= 1) {
    unsigned y = __shfl_up(v, off);
    if (t >= off) v += y;
  }
  if (t < NSCAN) bsum[t] = v - orig;   // exclusive
}

__global__ void scan3_k(const unsigned* __restrict__ loc, const unsigned* __restrict__ bsum,
                        const unsigned* __restrict__ cnt, unsigned* __restrict__ rowPtr,
                        unsigned* __restrict__ cursor, float* __restrict__ deg_inv) {
  int i = blockIdx.x * 256 + threadIdx.x;
  if (i < NN) {
    unsigned r = loc[i] + bsum[i >> 10];
    rowPtr[i] = r;
    cursor[i] = r;
    deg_inv[i] = 1.0f / fmaxf((float)cnt[i], 1.0f);
  }
  if (i == NN) rowPtr[NN] = (unsigned)NE;
}

__global__ void scat_k(const int* __restrict__ src, const int* __restrict__ dst,
                       unsigned* __restrict__ cursor, unsigned* __restrict__ perm,
                       int* __restrict__ srcS, int* __restrict__ dstS) {
  int e = blockIdx.x * 256 + threadIdx.x;
  int d = dst[e];
  unsigned pos = atomicAdd(&cursor[d], 1u);
  perm[pos] = (unsigned)e;
  srcS[pos] = src[e];
  dstS[pos] = d;
}

// ---------------- xform0: Hdp = h0@W1a, Hsp = h0@W1b from f32 hacc (sigma out) ----------------
__global__ __launch_bounds__(256) void node_xform_f32(
    const float* __restrict__ hsrc,
    const unsigned short* __restrict__ wpa, const unsigned short* __restrict__ wpb,
    unsigned short* __restrict__ Hdp, unsigned short* __restrict__ Hsp) {
  const int tid = threadIdx.x;
  const int wave = tid >> 6, lane = tid & 63;
  const int hi = lane >> 4, lo = lane & 15;
  const int n0w = blockIdx.x * 256 + wave * 64;

  u16x8 a[4][4];   // [s][mf]
  #pragma unroll
  for (int s = 0; s < 4; ++s)
    #pragma unroll
    for (int mf = 0; mf < 4; ++mf) {
      int n = n0w + 16 * mf + lo; if (n >= NN) n = NN - 1;
      f32x4 f0 = *(const f32x4*)(hsrc + (long)n * 128 + s * 32 + hi * 8);
      f32x4 f1 = *(const f32x4*)(hsrc + (long)n * 128 + s * 32 + hi * 8 + 4);
      u16x8 t;
      #pragma unroll
      for (int j = 0; j < 4; ++j) { t[j] = f2bf(f0[j]); t[4+j] = f2bf(f1[j]); }
      a[s][mf] = t;
    }

  #pragma unroll
  for (int out = 0; out < 2; ++out) {
    const unsigned short* wp = out ? wpb : wpa;
    unsigned short* dp = out ? Hsp : Hdp;
    f32x4 acc[4][8];
    #pragma unroll
    for (int mf = 0; mf < 4; ++mf)
      #pragma unroll
      for (int nb = 0; nb < 8; ++nb) acc[mf][nb] = (f32x4)(0.0f);
    #pragma unroll
    for (int s = 0; s < 4; ++s)
      #pragma unroll
      for (int nb = 0; nb < 8; ++nb) {
        u16x8 b = *(const u16x8*)(wp + ((s * 8 + nb) * 64 + lane) * 8);
        #pragma unroll
        for (int mf = 0; mf < 4; ++mf) acc[mf][nb] = mfma16(a[s][mf], b, acc[mf][nb]);
      }
    #pragma unroll
    for (int mf = 0; mf < 4; ++mf)
      #pragma unroll
      for (int r = 0; r < 4; ++r) {
        int n = n0w + 16 * mf + 4 * hi + r;
        if (n < NN) {
          u16x8 pack;
          #pragma unroll
          for (int nb = 0; nb < 8; ++nb) pack[nb] = f2bf(acc[mf][nb][r]);
          *(u16x8*)(dp + (long)n * 128 + 8 * lo) = pack;   // sigma: col 16nb+lo -> 8lo+nb
        }
      }
  }
}

// ---------------- node_xform16: Hdp = h@W1a, Hsp = h@W1b from bf16 h16 (sigma out) ----------
__global__ __launch_bounds__(256) void node_xform16(
    const unsigned short* __restrict__ h16,
    const unsigned short* __restrict__ wpa, const unsigned short* __restrict__ wpb,
    unsigned short* __restrict__ Hdp, unsigned short* __restrict__ Hsp) {
  const int tid = threadIdx.x;
  const int wave = tid >> 6, lane = tid & 63;
  const int hi = lane >> 4, lo = lane & 15;
  const int n0w = blockIdx.x * 256 + wave * 64;

  #pragma unroll
  for (int out = 0; out < 2; ++out) {
    const unsigned short* wp = out ? wpb : wpa;
    unsigned short* dp = out ? Hsp : Hdp;
    f32x4 acc[4][8];
    #pragma unroll
    for (int mf = 0; mf < 4; ++mf)
      #pragma unroll
      for (int nb = 0; nb < 8; ++nb) acc[mf][nb] = (f32x4)(0.0f);
    #pragma unroll
    for (int s = 0; s < 4; ++s) {
      u16x8 a[4];
      #pragma unroll
      for (int mf = 0; mf < 4; ++mf) {
        int n = n0w + 16 * mf + lo; if (n >= NN) n = NN - 1;
        a[mf] = *(const u16x8*)(h16 + (long)n * 128 + s * 32 + hi * 8);
      }
      #pragma unroll
      for (int nb = 0; nb < 8; ++nb) {
        u16x8 b = *(const u16x8*)(wp + ((s * 8 + nb) * 64 + lane) * 8);
        #pragma unroll
        for (int mf = 0; mf < 4; ++mf) acc[mf][nb] = mfma16(a[mf], b, acc[mf][nb]);
      }
    }
    #pragma unroll
    for (int mf = 0; mf < 4; ++mf)
      #pragma unroll
      for (int r = 0; r < 4; ++r) {
        int n = n0w + 16 * mf + 4 * hi + r;
        if (n < NN) {
          u16x8 pack;
          #pragma unroll
          for (int nb = 0; nb < 8; ++nb) pack[nb] = f2bf(acc[mf][nb][r]);
          *(u16x8*)(dp + (long)n * 128 + 8 * lo) = pack;   // sigma
        }
      }
  }
}

// ---------------- K12 (fused GEMM1+GEMM2+segment-sum, sorted edges) — R11-proven ----------
// hacc[dst] += deg_scaled( (relu(ea@W1 [+Hd+Hs] + b1))@W2 + b2 ) summed per dst run.
// Weights LDS-resident; asm-forced load pipeline; in-loop segsum w/ boundary atomics.
// LDS (dynamic 81920): [0,32K) W1; [32K,64K) W2; [64K,80K) 4 wave-stripes.
template<int EAM, bool EAST, bool GATH>
__global__ __launch_bounds__(256, 2) void k12_pass(
    const float* __restrict__ ea32, unsigned short* __restrict__ ea16,
    const unsigned* __restrict__ perm,
    const unsigned short* __restrict__ w1p, const unsigned short* __restrict__ w2p,
    const float* __restrict__ b1, const float* __restrict__ b2,
    const unsigned short* __restrict__ Hdp, const unsigned short* __restrict__ Hsp,
    const int* __restrict__ srcS, const int* __restrict__ dstS,
    const float* __restrict__ deg_inv, float* __restrict__ hacc) {
  extern __shared__ char smem[];
  const int tid = threadIdx.x;
  const int wave = tid >> 6, lane = tid & 63;
  const int hi = lane >> 4, lo = lane & 15;

  // bijective XCD swizzle: contiguous dst-chunk per XCD
  const int nwg = gridDim.x;
  const int xcd = blockIdx.x & 7, bbase = blockIdx.x >> 3;
  const int qc = nwg >> 3, rc = nwg & 7;
  const int bid = (xcd < rc ? xcd * (qc + 1) : rc * (qc + 1) + (xcd - rc) * qc) + bbase;
  const long e0w = (long)bid * 256 + wave * 64;
  char* sstripe = smem + 65536 + wave * 4096;

  constexpr int LB = (EAM == 0 ? 8 : 4) + (GATH ? 8 : 0);   // asm loads / batch

  unsigned pId[4];
  int dId[4], sId[4];
  float dsc[4];
  #pragma unroll
  for (int mf = 0; mf < 4; ++mf) {
    if (EAM == 0) pId[mf] = perm[e0w + 16 * mf + lo];
    dId[mf] = dstS[e0w + 16 * mf + lo];
    if (GATH) {
      sId[mf] = srcS[e0w + 16 * mf + lo];
      dsc[mf] = deg_inv[dId[mf]];
    }
  }

  float b1v[8], b2v[8];
  #pragma unroll
  for (int nb = 0; nb < 8; ++nb) { b1v[nb] = b1[nb * 16 + lo]; b2v[nb] = b2[nb * 16 + lo]; }

  // double-buffered operand sets (asm outputs — tied at the waits, can't be sunk)
  u16x8 eaA[4], eaB[4], gdA[4], gsA[4], gdB[4], gsB[4];
  f32x4 efA[8], efB[8];

  auto issue = [&](int mf, u16x8 (&ea)[4], f32x4 (&ef)[8],
                   u16x8 (&gd)[4], u16x8 (&gs)[4]) {
    if (EAM == 1) {
      #pragma unroll
      for (int s = 0; s < 4; ++s) {
        const unsigned short* p = ea16 + (e0w + 16 * mf + lo) * 128 + s * 32 + hi * 8;
        asm volatile("global_load_dwordx4 %0, %1, off" : "=&v"(ea[s]) : "v"(p) : "memory");
      }
    } else {
      #pragma unroll
      for (int s = 0; s < 4; ++s) {
        const float* p = ea32 + (long)pId[mf] * 128 + s * 32 + hi * 8;
        asm volatile("global_load_dwordx4 %0, %1, off" : "=&v"(ef[2*s])   : "v"(p)     : "memory");
        asm volatile("global_load_dwordx4 %0, %1, off" : "=&v"(ef[2*s+1]) : "v"(p + 4) : "memory");
      }
    }
    if (GATH) {
      #pragma unroll
      for (int r = 0; r < 4; ++r) {
        int rd = __shfl(dId[mf], 4 * hi + r);
        int rs = __shfl(sId[mf], 4 * hi + r);
        const unsigned short* pd = Hdp + (long)rd * 128 + 8 * lo;
        const unsigned short* ps = Hsp + (long)rs * 128 + 8 * lo;
        asm volatile("global_load_dwordx4 %0, %1, off" : "=&v"(gd[r]) : "v"(pd) : "memory");
        asm volatile("global_load_dwordx4 %0, %1, off" : "=&v"(gs[r]) : "v"(ps) : "memory");
      }
    }
  };

  issue(0, eaA, efA, gdA, gsA);   // batch0 lands under weight staging + barrier

  { // stage W1 + W2 into LDS (once)
    const u16x8* g1 = (const u16x8*)w1p;
    u16x8* l1 = (u16x8*)smem;
    #pragma unroll
    for (int i = 0; i < 8; ++i) l1[i * 256 + tid] = g1[i * 256 + tid];
    const u16x8* g2 = (const u16x8*)w2p;
    u16x8* l2 = (u16x8*)(smem + 32768);
    #pragma unroll
    for (int i = 0; i < 8; ++i) l2[i * 256 + tid] = g2[i * 256 + tid];
  }
  __syncthreads();

  // fused segment-sum state: lane owns 2 logical stripe positions -> 2 cols
  float runA = 0.0f, runB = 0.0f, scur = 1.0f;
  int dcur = -1;
  const int cA = 16 * ((2 * lane) & 7) + (lane >> 2);
  const int cB = 16 * ((2 * lane + 1) & 7) + (lane >> 2);

  #pragma unroll
  for (int mf = 0; mf < 4; ++mf) {
    u16x8 (&ea)[4] = (mf & 1) ? eaB : eaA;
    f32x4 (&ef)[8] = (mf & 1) ? efB : efA;
    u16x8 (&gd)[4] = (mf & 1) ? gdB : gdA;
    u16x8 (&gs)[4] = (mf & 1) ? gsB : gsA;
    if (mf < 3)
      issue(mf + 1, (mf & 1) ? eaA : eaB, (mf & 1) ? efA : efB,
            (mf & 1) ? gdA : gdB, (mf & 1) ? gsA : gsB);

    // gate on batch(mf); credit only batch(mf+1) loads (atomics are data-dependent)
    if (EAM == 1) {
      if (GATH) {
        asm volatile("s_waitcnt vmcnt(%12)"
          : "+v"(ea[0]), "+v"(ea[1]), "+v"(ea[2]), "+v"(ea[3]),
            "+v"(gd[0]), "+v"(gd[1]), "+v"(gd[2]), "+v"(gd[3]),
            "+v"(gs[0]), "+v"(gs[1]), "+v"(gs[2]), "+v"(gs[3])
          : "n"(mf < 3 ? LB : 0));
      } else {
        asm volatile("s_waitcnt vmcnt(%4)"
          : "+v"(ea[0]), "+v"(ea[1]), "+v"(ea[2]), "+v"(ea[3])
          : "n"(mf < 3 ? LB : 0));
      }
    } else if (GATH) {
      asm volatile("s_waitcnt vmcnt(%16)"
        : "+v"(ef[0]), "+v"(ef[1]), "+v"(ef[2]), "+v"(ef[3]),
          "+v"(ef[4]), "+v"(ef[5]), "+v"(ef[6]), "+v"(ef[7]),
          "+v"(gd[0]), "+v"(gd[1]), "+v"(gd[2]), "+v"(gd[3]),
          "+v"(gs[0]), "+v"(gs[1]), "+v"(gs[2]), "+v"(gs[3])
        : "n"(mf < 3 ? LB : 0));
    } else {
      asm volatile("s_waitcnt vmcnt(%8)"
        : "+v"(ef[0]), "+v"(ef[1]), "+v"(ef[2]), "+v"(ef[3]),
          "+v"(ef[4]), "+v"(ef[5]), "+v"(ef[6]), "+v"(ef[7])
        : "n"(mf < 3 ? LB : 0));
    }

    if (EAM == 0) {   // convert f32 -> bf16 (and optionally store sorted ea16)
      #pragma unroll
      for (int s = 0; s < 4; ++s) {
        u16x8 t;
        #pragma unroll
        for (int j = 0; j < 4; ++j) { t[j] = f2bf(ef[2*s][j]); t[4+j] = f2bf(ef[2*s+1][j]); }
        if (EAST)
          *(u16x8*)(ea16 + (e0w + 16 * mf + lo) * 128 + s * 32 + hi * 8) = t;
        ea[s] = t;
      }
    }

    // ---- GEMM1 (acc starts at 0; gathers added after) ----
    f32x4 acc[8];
    #pragma unroll
    for (int nb = 0; nb < 8; ++nb) acc[nb] = (f32x4)(0.0f);
    #pragma unroll
    for (int s = 0; s < 4; ++s)
      #pragma unroll
      for (int nb = 0; nb < 8; ++nb) {
        u16x8 b = *(const u16x8*)(smem + ((s * 8 + nb) << 10) + (lane << 4));
        acc[nb] = mfma16(ea[s], b, acc[nb]);
      }
    if (GATH) {
      #pragma unroll
      for (int nb = 0; nb < 8; ++nb)
        #pragma unroll
        for (int r = 0; r < 4; ++r)
          acc[nb][r] += bf2f(gd[r][nb]) + bf2f(gs[r][nb]);
    }

    // ---- epilogue1: bias+relu -> bf16 -> sigma stripe ----
    #pragma unroll
    for (int r = 0; r < 4; ++r) {
      int er = 4 * hi + r;
      u16x8 pack;
      #pragma unroll
      for (int nb = 0; nb < 8; ++nb)
        pack[nb] = f2bf(fmaxf(acc[nb][r] + b1v[nb], 0.0f));
      *(u16x8*)(sstripe + er * 256 + ((lo * 16) ^ ((er & 7) << 4))) = pack;
    }

    // ---- GEMM2 (wave-private stripe, no barrier) ----
    f32x4 acc2[8];
    #pragma unroll
    for (int nb = 0; nb < 8; ++nb) acc2[nb] = (f32x4)(0.0f);
    #pragma unroll
    for (int s2 = 0; s2 < 4; ++s2) {
      u16x8 a = *(const u16x8*)(sstripe + lo * 256 +
                                (((4 * s2 + hi) * 16) ^ ((lo & 7) << 4)));
      #pragma unroll
      for (int nb = 0; nb < 8; ++nb) {
        u16x8 b = *(const u16x8*)(smem + 32768 + ((s2 * 8 + nb) << 10) + (lane << 4));
        acc2[nb] = mfma16(a, b, acc2[nb]);
      }
    }

    // ---- epilogue2: +bias -> bf16 -> stripe (m values, sigma positions) ----
    #pragma unroll
    for (int r = 0; r < 4; ++r) {
      int er = 4 * hi + r;
      u16x8 pack;
      #pragma unroll
      for (int nb = 0; nb < 8; ++nb)
        pack[nb] = f2bf(acc2[nb][r] + b2v[nb]);
      *(u16x8*)(sstripe + er * 256 + ((lo * 16) ^ ((er & 7) << 4))) = pack;
    }

    // ---- fused segment-sum over stripe rows (dst-sorted; wave-uniform runs) ----
    #pragma unroll
    for (int er = 0; er < 16; ++er) {
      int d = __shfl(dId[mf], er);
      float s = GATH ? __shfl(dsc[mf], er) : 1.0f;
      if (d != dcur) {
        if (dcur >= 0) {
          unsafeAtomicAdd(&hacc[(long)dcur * 128 + cA], runA * scur);
          unsafeAtomicAdd(&hacc[(long)dcur * 128 + cB], runB * scur);
        }
        runA = 0.0f; runB = 0.0f; dcur = d; scur = s;
      }
      unsigned pr = *(const unsigned*)(sstripe + er * 256 +
                                       ((lane * 4) ^ ((er & 7) << 4)));
      runA += bf2f((unsigned short)(pr & 0xffffu));
      runB += bf2f((unsigned short)(pr >> 16));
    }
  }
  // final flush
  if (dcur >= 0) {
    unsafeAtomicAdd(&hacc[(long)dcur * 128 + cA], runA * scur);
    unsafeAtomicAdd(&hacc[(long)dcur * 128 + cB], runB * scur);
  }
}

// ---------------- node MLP: h16 = relu(agg @ Wn + bn) ----------------
__global__ __launch_bounds__(256) void node_pass(
    const float* __restrict__ agg, const unsigned short* __restrict__ wp,
    const float* __restrict__ bias, unsigned short* __restrict__ h16out) {
  __shared__ char smem[49152];
  const int tid = threadIdx.x;
  const int wave = tid >> 6, lane = tid & 63;
  const int hi = lane >> 4, lo = lane & 15;
  const int n0 = blockIdx.x * 64;
  const int r = tid >> 2, q = tid & 3;

  #pragma unroll
  for (int s = 0; s < 4; ++s) {
    f32x4 f0 = *(const f32x4*)(agg + (long)(n0 + r) * 128 + s * 32 + q * 8);
    f32x4 f1 = *(const f32x4*)(agg + (long)(n0 + r) * 128 + s * 32 + q * 8 + 4);
    u16x8 t;
    #pragma unroll
    for (int j = 0; j < 4; ++j) { t[j] = f2bf(f0[j]); t[4+j] = f2bf(f1[j]); }
    *(u16x8*)(smem + s * 4096 + (((r >> 4) * 64 + q * 16 + (r & 15)) << 4)) = t;
  }
  {
    const u16x8* g = (const u16x8*)wp;
    u16x8* l = (u16x8*)(smem + 16384);
    #pragma unroll
    for (int i = 0; i < 8; ++i) l[i * 256 + tid] = g[i * 256 + tid];
  }
  __syncthreads();

  f32x4 acc[8];
  #pragma unroll
  for (int nb = 0; nb < 8; ++nb) acc[nb] = (f32x4)(0.0f);
  #pragma unroll
  for (int s = 0; s < 4; ++s) {
    u16x8 a = *(const u16x8*)(smem + s * 4096 + wave * 1024 + (lane << 4));
    #pragma unroll
    for (int nb = 0; nb < 8; ++nb) {
      u16x8 b = *(const u16x8*)(smem + 16384 + ((s * 8 + nb) << 10) + (lane << 4));
      acc[nb] = mfma16(a, b, acc[nb]);
    }
  }
  float bv[8];
  #pragma unroll
  for (int nb = 0; nb < 8; ++nb) bv[nb] = bias[nb * 16 + lo];
  #pragma unroll
  for (int nb = 0; nb < 8; ++nb)
    #pragma unroll
    for (int rr = 0; rr < 4; ++rr) {
      int node = n0 + 16 * wave + 4 * hi + rr;
      float v = fmaxf(acc[nb][rr] + bv[nb], 0.0f);
      h16out[(long)node * 128 + nb * 16 + lo] = f2bf(v);
    }
}

// ---------------- output head ----------------
__global__ __launch_bounds__(256) void out_pass(
    const unsigned short* __restrict__ h16, const unsigned short* __restrict__ wp,
    const float* __restrict__ ob1, const float* __restrict__ oW2,
    const float* __restrict__ ob2, float* __restrict__ out) {
  __shared__ char smem[49152];
  const int tid = threadIdx.x;
  const int wave = tid >> 6, lane = tid & 63;
  const int hi = lane >> 4, lo = lane & 15;
  const int n0 = blockIdx.x * 64;
  const int r = tid >> 2, q = tid & 3;

  #pragma unroll
  for (int s = 0; s < 4; ++s) {
    u16x8 t = *(const u16x8*)(h16 + (long)(n0 + r) * 128 + s * 32 + q * 8);
    *(u16x8*)(smem + s * 4096 + (((r >> 4) * 64 + q * 16 + (r & 15)) << 4)) = t;
  }
  {
    const u16x8* g = (const u16x8*)wp;
    u16x8* l = (u16x8*)(smem + 16384);
    #pragma unroll
    for (int i = 0; i < 8; ++i) l[i * 256 + tid] = g[i * 256 + tid];
  }
  __syncthreads();

  f32x4 acc[8];
  #pragma unroll
  for (int nb = 0; nb < 8; ++nb) acc[nb] = (f32x4)(0.0f);
  #pragma unroll
  for (int s = 0; s < 4; ++s) {
    u16x8 a = *(const u16x8*)(smem + s * 4096 + wave * 1024 + (lane << 4));
    #pragma unroll
    for (int nb = 0; nb < 8; ++nb) {
      u16x8 b = *(const u16x8*)(smem + 16384 + ((s * 8 + nb) << 10) + (lane << 4));
      acc[nb] = mfma16(a, b, acc[nb]);
    }
  }
  float b1v[8], w2v[8][3];
  #pragma unroll
  for (int nb = 0; nb < 8; ++nb) {
    b1v[nb] = ob1[nb * 16 + lo];
    #pragma unroll
    for (int o = 0; o < 3; ++o) w2v[nb][o] = oW2[(nb * 16 + lo) * 3 + o];
  }
  #pragma unroll
  for (int rr = 0; rr < 4; ++rr) {
    float p0 = 0.f, p1 = 0.f, p2 = 0.f;
    #pragma unroll
    for (int nb = 0; nb < 8; ++nb) {
      float t = fmaxf(acc[nb][rr] + b1v[nb], 0.0f);
      p0 += t * w2v[nb][0]; p1 += t * w2v[nb][1]; p2 += t * w2v[nb][2];
    }
    #pragma unroll
    for (int off = 1; off < 16; off <<= 1) {
      p0 += __shfl_xor(p0, off); p1 += __shfl_xor(p1, off); p2 += __shfl_xor(p2, off);
    }
    if (lo == 0) {
      int node = n0 + 16 * wave + 4 * hi + rr;
      out[(long)node * 3 + 0] = p0 + ob2[0];
      out[(long)node * 3 + 1] = p1 + ob2[1];
      out[(long)node * 3 + 2] = p2 + ob2[2];
    }
  }
}

// ---------------- host ----------------
extern "C" void kernel_launch(void* const* d_in, const int* in_sizes, int n_in,
                              void* d_out, int out_size, void* d_ws, size_t ws_size,
                              hipStream_t stream) {
  const int*   ei     = (const int*)d_in[1];
  const int*   srcIds = ei;
  const int*   dstIds = ei + NE;
  const float* ea     = (const float*)d_in[2];
  const float* e2nb1  = (const float*)d_in[4];
  const float* e2nb2  = (const float*)d_in[6];
  const float* eW1    = (const float*)d_in[7];
  const float* eb1    = (const float*)d_in[8];
  const float* eW2    = (const float*)d_in[9];
  const float* eb2    = (const float*)d_in[10];
  const float* nW     = (const float*)d_in[11];
  const float* nb_    = (const float*)d_in[12];
  const float* ob1    = (const float*)d_in[14];
  const float* oW2    = (const float*)d_in[15];
  const float* ob2    = (const float*)d_in[16];
  float* out = (float*)d_out;

  char* ws = (char*)d_ws;
  float* hacc = (float*)(ws + O_HACC);
  unsigned short* h16 = (unsigned short*)(ws + O_H16);
  float* deg_inv = (float*)(ws + O_DEG);
  unsigned short* wp = (unsigned short*)(ws + O_WP);
  unsigned short* Hdp = (unsigned short*)(ws + O_HDP);
  unsigned short* Hsp = (unsigned short*)(ws + O_HSP);
  unsigned* cnt    = (unsigned*)(ws + O_CNT);
  unsigned* loc    = (unsigned*)(ws + O_LOC);
  unsigned* rowPtr = (unsigned*)(ws + O_ROWP);
  unsigned* cursor = (unsigned*)(ws + O_CURS);
  unsigned* bsum   = (unsigned*)(ws + O_BSUM);
  unsigned* perm   = (unsigned*)(ws + O_PERM);
  int* srcS        = (int*)(ws + O_SRCS);
  int* dstS        = (int*)(ws + O_DSTS);
  unsigned short* ea16 = (unsigned short*)(ws + O_EA16);
  const bool tier2 = ws_size >= (size_t)NEED_T2;

  PrepPtrs pp;
  pp.p[0] = (const float*)d_in[3];
  pp.p[1] = (const float*)d_in[5];
  for (int l = 0; l < 3; ++l) {
    pp.p[2 + 3*l] = eW1 + l * 49152;             // W1a (A)
    pp.p[3 + 3*l] = eW1 + l * 49152 + 16384;     // W1b (A)
    pp.p[4 + 3*l] = eW1 + l * 49152 + 32768;     // W1c (A)
    pp.p[11 + l]  = eW2 + l * 16384;             // W2 (kappa)
    pp.p[14 + l]  = nW  + l * 16384;             // nW (A)
  }
  pp.p[17] = (const float*)d_in[13];

  prep_all<<<dim3(64, 18), 256, 0, stream>>>(pp, wp);

  // counting sort by dst + deg_inv
  hipMemsetAsync(cnt, 0, (size_t)NN * 4, stream);
  hist_k<<<NE / 256, 256, 0, stream>>>(dstIds, cnt);
  scan1_k<<<NSCAN, 256, 0, stream>>>(cnt, loc, bsum);
  scan2_k<<<1, 64, 0, stream>>>(bsum);
  scan3_k<<<(NN + 256) / 256, 256, 0, stream>>>(loc, bsum, cnt, rowPtr, cursor, deg_inv);
  scat_k<<<NE / 256, 256, 0, stream>>>(srcIds, dstIds, cursor, perm, srcS, dstS);

  // ---- e2n: fused edge-MLP + scatter-sum -> hacc = h0 (f32) ----
  hipMemsetAsync(hacc, 0, (size_t)NN * H * 4, stream);
  if (tier2)
    k12_pass<0, true, false><<<NE / 256, 256, 81920, stream>>>(
        ea, ea16, perm, wpm(wp, 0), wpm(wp, 1), e2nb1, e2nb2,
        nullptr, nullptr, srcS, dstS, deg_inv, hacc);
  else
    k12_pass<0, false, false><<<NE / 256, 256, 81920, stream>>>(
        ea, nullptr, perm, wpm(wp, 0), wpm(wp, 1), e2nb1, e2nb2,
        nullptr, nullptr, srcS, dstS, deg_inv, hacc);

  // xform0: Hdp/Hsp for layer 0 straight from f32 h0 (no cvt_h0 round-trip)
  node_xform_f32<<<(NN + 255) / 256, 256, 0, stream>>>(
      hacc, wpm(wp, 2), wpm(wp, 3), Hdp, Hsp);

  for (int l = 0; l < 3; ++l) {
    hipMemsetAsync(hacc, 0, (size_t)NN * H * 4, stream);
    if (tier2)
      k12_pass<1, false, true><<<NE / 256, 256, 81920, stream>>>(
          ea, ea16, perm, wpm(wp, 4 + 3*l), wpm(wp, 11 + l),
          eb1 + l * 128, eb2 + l * 128, Hdp, Hsp, srcS, dstS, deg_inv, hacc);
    else
      k12_pass<0, false, true><<<NE / 256, 256, 81920, stream>>>(
          ea, nullptr, perm, wpm(wp, 4 + 3*l), wpm(wp, 11 + l),
          eb1 + l * 128, eb2 + l * 128, Hdp, Hsp, srcS, dstS, deg_inv, hacc);
    node_pass<<<NN / 64, 256, 0, stream>>>(hacc, wpm(wp, 14 + l),
                                           nb_ + l * 128, h16);
    if (l < 2)
      node_xform16<<<(NN + 255) / 256, 256, 0, stream>>>(
          h16, wpm(wp, 5 + 3*l), wpm(wp, 6 + 3*l), Hdp, Hsp);
  }

  out_pass<<<NN / 64, 256, 0, stream>>>(h16, wpm(wp, 17), ob1, oW2, ob2, out);
}